// Round 1
// baseline (1655.076 us; speedup 1.0000x reference)
//
#include <hip/hip_runtime.h>

#define NN 10000
#define NE 160000
#define IND 56          // 32 + 3*8
#define EF 64
#define HID 64
#define WN 1600

static constexpr float PATH_NORM_C = 0.15811388300841897f; // 1/sqrt(40)
static constexpr float CG_C        = 0.57735026918962576f; // 1/sqrt(3)

__global__ __launch_bounds__(256, 1) void edge_tp_kernel(
    const float* __restrict__ node_attr,
    const float* __restrict__ edge_attr,
    const float* __restrict__ edge_sh,
    const float* __restrict__ fc_w1,
    const float* __restrict__ fc_b1,
    const float* __restrict__ fc_w2,
    const float* __restrict__ fc_b2,
    const int*   __restrict__ edge_index,
    float* __restrict__ acc,   // [NN*56]
    float* __restrict__ cnt)   // [NN]
{
    const int e = blockIdx.x * 256 + threadIdx.x;
    if (e >= NE) return;
    const int src = edge_index[e];
    const int dst = edge_index[NE + e];

    // ---------------- GEMM1: h = relu(edge_attr[e] @ fc_w1 + fc_b1) ----------
    float h[HID];
    #pragma unroll
    for (int k = 0; k < HID; ++k) h[k] = fc_b1[k];
    {
        const float4* eap = reinterpret_cast<const float4*>(edge_attr) + e * (EF / 4);
        #pragma unroll 1
        for (int j4 = 0; j4 < EF / 4; ++j4) {
            const float4 a = eap[j4];
            const float* wr = fc_w1 + (j4 * 4) * HID;
            #pragma unroll
            for (int k = 0; k < HID; ++k) h[k] += a.x * wr[k];
            #pragma unroll
            for (int k = 0; k < HID; ++k) h[k] += a.y * wr[HID + k];
            #pragma unroll
            for (int k = 0; k < HID; ++k) h[k] += a.z * wr[2 * HID + k];
            #pragma unroll
            for (int k = 0; k < HID; ++k) h[k] += a.w * wr[3 * HID + k];
        }
    }
    #pragma unroll
    for (int k = 0; k < HID; ++k) h[k] = fmaxf(h[k], 0.0f);

    // ---------------- gather x = node_attr[dst], sh ---------------------------
    float x0[32], x1[24];
    {
        const float4* xp = reinterpret_cast<const float4*>(node_attr + (size_t)dst * IND);
        #pragma unroll
        for (int i = 0; i < 8; ++i) {
            const float4 v = xp[i];
            x0[4*i] = v.x; x0[4*i+1] = v.y; x0[4*i+2] = v.z; x0[4*i+3] = v.w;
        }
        #pragma unroll
        for (int i = 0; i < 6; ++i) {
            const float4 v = xp[8 + i];
            x1[4*i] = v.x; x1[4*i+1] = v.y; x1[4*i+2] = v.z; x1[4*i+3] = v.w;
        }
    }
    const float4 shv = reinterpret_cast<const float4*>(edge_sh)[e];
    const float s0 = shv.x, s1x = shv.y, s1y = shv.z, s1z = shv.w;

    float y1[8];
    #pragma unroll
    for (int u = 0; u < 8; ++u)
        y1[u] = CG_C * (x1[3*u] * s1x + x1[3*u+1] * s1y + x1[3*u+2] * s1z);

    // w-block helper: w[v] = fc_b2[j0+v] + sum_k h[k] * fc_w2[k*1600 + j0 + v]
    auto compute_w8 = [&](int j0, float* w) {
        #pragma unroll
        for (int v = 0; v < 8; ++v) w[v] = fc_b2[j0 + v];
        const float* p = fc_w2 + j0;
        #pragma unroll 4
        for (int k = 0; k < HID; ++k) {
            const float hk = h[k];
            #pragma unroll
            for (int v = 0; v < 8; ++v) w[v] += hk * p[v];
            p += WN;
        }
    };

    // ---------------- region w1: j = u*32+v  -> out0[v] += s0*x0[u]*w --------
    float out0[32];
    #pragma unroll
    for (int v = 0; v < 32; ++v) out0[v] = 0.0f;

    #pragma unroll 1
    for (int u = 0; u < 32; ++u) {
        const float c = s0 * x0[u];
        #pragma unroll 1
        for (int vb = 0; vb < 4; ++vb) {
            float w[8];
            compute_w8(u * 32 + vb * 8, w);
            #pragma unroll
            for (int v = 0; v < 8; ++v) out0[vb * 8 + v] += c * w[v];
        }
    }

    // ---------------- region w2: j = 1024+u*8+v -> t[v] += x0[u]*w -----------
    float tt[8];
    #pragma unroll
    for (int v = 0; v < 8; ++v) tt[v] = 0.0f;
    #pragma unroll 1
    for (int u = 0; u < 32; ++u) {
        float w[8];
        compute_w8(1024 + u * 8, w);
        const float c = x0[u];
        #pragma unroll
        for (int v = 0; v < 8; ++v) tt[v] += c * w[v];
    }

    // ------ region w3: j = 1280+u*8+v -> o1[v][m] += s0*x1[u][m]*w -----------
    float o1[24];
    #pragma unroll
    for (int i = 0; i < 24; ++i) o1[i] = 0.0f;
    #pragma unroll 1
    for (int u = 0; u < 8; ++u) {
        float w[8];
        compute_w8(1280 + u * 8, w);
        #pragma unroll
        for (int v = 0; v < 8; ++v) {
            const float d = s0 * w[v];
            o1[3*v+0] += d * x1[3*u+0];
            o1[3*v+1] += d * x1[3*u+1];
            o1[3*v+2] += d * x1[3*u+2];
        }
    }

    // ------ region w4: j = 1344+u*32+v -> out0[v] += CG*y1[u]*w --------------
    #pragma unroll 1
    for (int u = 0; u < 8; ++u) {
        const float c = y1[u];   // CG already folded into y1
        #pragma unroll 1
        for (int vb = 0; vb < 4; ++vb) {
            float w[8];
            compute_w8(1344 + u * 32 + vb * 8, w);
            #pragma unroll
            for (int v = 0; v < 8; ++v) out0[vb * 8 + v] += c * w[v];
        }
    }

    // ---------------- scatter-accumulate -------------------------------------
    float* ap = acc + (size_t)src * IND;
    #pragma unroll
    for (int v = 0; v < 32; ++v) atomicAdd(ap + v, PATH_NORM_C * out0[v]);
    #pragma unroll
    for (int v = 0; v < 8; ++v) {
        const float tv = tt[v];
        atomicAdd(ap + 32 + 3*v + 0, PATH_NORM_C * (o1[3*v+0] + s1x * tv));
        atomicAdd(ap + 32 + 3*v + 1, PATH_NORM_C * (o1[3*v+1] + s1y * tv));
        atomicAdd(ap + 32 + 3*v + 2, PATH_NORM_C * (o1[3*v+2] + s1z * tv));
    }
    atomicAdd(cnt + src, 1.0f);
}

__global__ __launch_bounds__(256) void finalize_kernel(
    const float* __restrict__ acc,
    const float* __restrict__ cnt,
    const float* __restrict__ node_attr,
    float* __restrict__ out)
{
    const int i = blockIdx.x * 256 + threadIdx.x;
    if (i >= NN * IND) return;
    const int n = i / IND;
    const float c = fmaxf(cnt[n], 1.0f);
    out[i] = acc[i] / c + node_attr[i];
}

extern "C" void kernel_launch(void* const* d_in, const int* in_sizes, int n_in,
                              void* d_out, int out_size, void* d_ws, size_t ws_size,
                              hipStream_t stream) {
    const float* node_attr = (const float*)d_in[0];
    const float* edge_attr = (const float*)d_in[1];
    const float* edge_sh   = (const float*)d_in[2];
    const float* fc_w1     = (const float*)d_in[3];
    const float* fc_b1     = (const float*)d_in[4];
    const float* fc_w2     = (const float*)d_in[5];
    const float* fc_b2     = (const float*)d_in[6];
    const int*   edge_index = (const int*)d_in[7];

    float* acc = (float*)d_ws;
    float* cnt = acc + (size_t)NN * IND;

    hipMemsetAsync(d_ws, 0, ((size_t)NN * IND + NN) * sizeof(float), stream);

    edge_tp_kernel<<<(NE + 255) / 256, 256, 0, stream>>>(
        node_attr, edge_attr, edge_sh, fc_w1, fc_b1, fc_w2, fc_b2, edge_index,
        acc, cnt);

    finalize_kernel<<<(NN * IND + 255) / 256, 256, 0, stream>>>(
        acc, cnt, node_attr, (float*)d_out);
}

// Round 2
// 1264.555 us; speedup vs baseline: 1.3088x; 1.3088x over previous
//
#include <hip/hip_runtime.h>

#define NN 10000
#define NE 160000
#define IND 56          // 32 + 3*8
#define EF 64
#define HID 64
#define WN 1600
#define TPB 128

static constexpr float PATH_NORM_C = 0.15811388300841897f; // 1/sqrt(40)
static constexpr float CG_C        = 0.57735026918962576f; // 1/sqrt(3)

__global__ __launch_bounds__(TPB) void edge_tp_kernel(
    const float* __restrict__ node_attr,
    const float* __restrict__ edge_attr,
    const float* __restrict__ edge_sh,
    const float* __restrict__ fc_w1,
    const float* __restrict__ fc_b1,
    const float* __restrict__ fc_w2,
    const float* __restrict__ fc_b2,
    const int*   __restrict__ edge_index,
    float* __restrict__ acc,   // [NN*56]
    float* __restrict__ cnt)   // [NN]
{
    // Coefficient table in LDS, transposed [row][tid] so dynamic row index is
    // legal (LDS) and reads are uniform-row/per-lane-tid -> 2-way banked (free).
    // rows 0..31 : x0[u]
    // rows 32..39: y1[u] = CG * (x1[u] . s1)    (region-4 coefficient)
    // rows 40..63: s0 * x1[u][m]                (region-3 coefficient)
    __shared__ float cf[64][TPB];

    const int tid = threadIdx.x;
    const int e = blockIdx.x * TPB + tid;
    if (e >= NE) return;
    const int src = edge_index[e];
    const int dst = edge_index[NE + e];

    const float4 shv = reinterpret_cast<const float4*>(edge_sh)[e];
    const float s0 = shv.x, s1x = shv.y, s1y = shv.z, s1z = shv.w;

    // ---- gather node features -> LDS coefficient columns (own column only,
    //      no cross-thread sharing -> no barrier needed) ---------------------
    {
        const float4* xp = reinterpret_cast<const float4*>(node_attr + (size_t)dst * IND);
        float xr[56];
        #pragma unroll
        for (int i = 0; i < 14; ++i) {
            const float4 v = xp[i];
            xr[4*i] = v.x; xr[4*i+1] = v.y; xr[4*i+2] = v.z; xr[4*i+3] = v.w;
        }
        #pragma unroll
        for (int u = 0; u < 32; ++u) cf[u][tid] = xr[u];
        #pragma unroll
        for (int u = 0; u < 8; ++u)
            cf[32 + u][tid] = CG_C * (xr[32+3*u] * s1x + xr[32+3*u+1] * s1y + xr[32+3*u+2] * s1z);
        #pragma unroll
        for (int i = 0; i < 24; ++i) cf[40 + i][tid] = s0 * xr[32 + i];
    }

    // ---- GEMM1: h = relu(edge_attr[e] @ fc_w1 + fc_b1), h fully in VGPRs ----
    float h[HID];
    #pragma unroll
    for (int k = 0; k < HID; ++k) h[k] = fc_b1[k];
    {
        const float4* eap = reinterpret_cast<const float4*>(edge_attr) + e * (EF / 4);
        #pragma unroll 1
        for (int j4 = 0; j4 < EF / 4; ++j4) {
            const float4 a = eap[j4];
            const float* wr = fc_w1 + (j4 * 4) * HID;   // wave-uniform address
            #pragma unroll
            for (int k = 0; k < HID; ++k) h[k] = fmaf(a.x, wr[k],           h[k]);
            #pragma unroll
            for (int k = 0; k < HID; ++k) h[k] = fmaf(a.y, wr[HID + k],     h[k]);
            #pragma unroll
            for (int k = 0; k < HID; ++k) h[k] = fmaf(a.z, wr[2 * HID + k], h[k]);
            #pragma unroll
            for (int k = 0; k < HID; ++k) h[k] = fmaf(a.w, wr[3 * HID + k], h[k]);
        }
    }
    #pragma unroll
    for (int k = 0; k < HID; ++k) h[k] = fmaxf(h[k], 0.0f);

    // w-block: w[v] = fc_b2[j0+v] + sum_k h[k]*fc_w2[k*WN+j0+v]; k FULLY
    // unrolled so h[] stays static-indexed (registers). Addresses uniform.
    auto compute_w8 = [&](int j0, float* w) {
        #pragma unroll
        for (int v = 0; v < 8; ++v) w[v] = fc_b2[j0 + v];
        const float* p = fc_w2 + j0;
        #pragma unroll
        for (int k = 0; k < HID; ++k) {
            #pragma unroll
            for (int v = 0; v < 8; ++v) w[v] = fmaf(h[k], p[k * WN + v], w[v]);
        }
    };

    float out0[32];
    #pragma unroll
    for (int v = 0; v < 32; ++v) out0[v] = 0.0f;

    // ---- region w1: j = u*32+v -> out0[v] += s0*x0[u]*w --------------------
    // vb unrolled (static out0 index), u rolled (coef via LDS).
    #pragma unroll
    for (int vb = 0; vb < 4; ++vb) {
        #pragma unroll 1
        for (int u = 0; u < 32; ++u) {
            const float c = s0 * cf[u][tid];
            float w[8];
            compute_w8(u * 32 + vb * 8, w);
            #pragma unroll
            for (int v = 0; v < 8; ++v) out0[vb * 8 + v] = fmaf(c, w[v], out0[vb * 8 + v]);
        }
    }

    // ---- region w2: j = 1024+u*8+v -> tt[v] += x0[u]*w ---------------------
    float tt[8];
    #pragma unroll
    for (int v = 0; v < 8; ++v) tt[v] = 0.0f;
    #pragma unroll 1
    for (int u = 0; u < 32; ++u) {
        const float c = cf[u][tid];
        float w[8];
        compute_w8(1024 + u * 8, w);
        #pragma unroll
        for (int v = 0; v < 8; ++v) tt[v] = fmaf(c, w[v], tt[v]);
    }

    // ---- region w3: j = 1280+u*8+v -> o1[v][m] += (s0*x1[u][m])*w ----------
    float o1[24];
    #pragma unroll
    for (int i = 0; i < 24; ++i) o1[i] = 0.0f;
    #pragma unroll 1
    for (int u = 0; u < 8; ++u) {
        float w[8];
        compute_w8(1280 + u * 8, w);
        const float c0 = cf[40 + 3*u + 0][tid];
        const float c1 = cf[40 + 3*u + 1][tid];
        const float c2 = cf[40 + 3*u + 2][tid];
        #pragma unroll
        for (int v = 0; v < 8; ++v) {
            o1[3*v+0] = fmaf(w[v], c0, o1[3*v+0]);
            o1[3*v+1] = fmaf(w[v], c1, o1[3*v+1]);
            o1[3*v+2] = fmaf(w[v], c2, o1[3*v+2]);
        }
    }

    // ---- region w4: j = 1344+u*32+v -> out0[v] += y1[u]*w ------------------
    #pragma unroll
    for (int vb = 0; vb < 4; ++vb) {
        #pragma unroll 1
        for (int u = 0; u < 8; ++u) {
            const float c = cf[32 + u][tid];   // CG already folded in
            float w[8];
            compute_w8(1344 + u * 32 + vb * 8, w);
            #pragma unroll
            for (int v = 0; v < 8; ++v) out0[vb * 8 + v] = fmaf(c, w[v], out0[vb * 8 + v]);
        }
    }

    // ---- scatter-accumulate ------------------------------------------------
    float* ap = acc + (size_t)src * IND;
    #pragma unroll
    for (int v = 0; v < 32; ++v) atomicAdd(ap + v, PATH_NORM_C * out0[v]);
    #pragma unroll
    for (int v = 0; v < 8; ++v) {
        const float tv = tt[v];
        atomicAdd(ap + 32 + 3*v + 0, PATH_NORM_C * (o1[3*v+0] + s1x * tv));
        atomicAdd(ap + 32 + 3*v + 1, PATH_NORM_C * (o1[3*v+1] + s1y * tv));
        atomicAdd(ap + 32 + 3*v + 2, PATH_NORM_C * (o1[3*v+2] + s1z * tv));
    }
    atomicAdd(cnt + src, 1.0f);
}

__global__ __launch_bounds__(256) void finalize_kernel(
    const float* __restrict__ acc,
    const float* __restrict__ cnt,
    const float* __restrict__ node_attr,
    float* __restrict__ out)
{
    const int i = blockIdx.x * 256 + threadIdx.x;
    if (i >= NN * IND) return;
    const int n = i / IND;
    const float c = fmaxf(cnt[n], 1.0f);
    out[i] = acc[i] / c + node_attr[i];
}

extern "C" void kernel_launch(void* const* d_in, const int* in_sizes, int n_in,
                              void* d_out, int out_size, void* d_ws, size_t ws_size,
                              hipStream_t stream) {
    const float* node_attr = (const float*)d_in[0];
    const float* edge_attr = (const float*)d_in[1];
    const float* edge_sh   = (const float*)d_in[2];
    const float* fc_w1     = (const float*)d_in[3];
    const float* fc_b1     = (const float*)d_in[4];
    const float* fc_w2     = (const float*)d_in[5];
    const float* fc_b2     = (const float*)d_in[6];
    const int*   edge_index = (const int*)d_in[7];

    float* acc = (float*)d_ws;
    float* cnt = acc + (size_t)NN * IND;

    hipMemsetAsync(d_ws, 0, ((size_t)NN * IND + NN) * sizeof(float), stream);

    edge_tp_kernel<<<NE / TPB, TPB, 0, stream>>>(
        node_attr, edge_attr, edge_sh, fc_w1, fc_b1, fc_w2, fc_b2, edge_index,
        acc, cnt);

    finalize_kernel<<<(NN * IND + 255) / 256, 256, 0, stream>>>(
        acc, cnt, node_attr, (float*)d_out);
}

// Round 3
// 216.125 us; speedup vs baseline: 7.6579x; 5.8510x over previous
//
#include <hip/hip_runtime.h>

#define NN 10000
#define NE 160000
#define IND 56          // 32 + 3*8
#define WN 1600
#define EPB 128         // edges per block (4 waves x 32)
#define NBLK (NE / EPB) // 1250

typedef __attribute__((ext_vector_type(8))) short bf16x8;
typedef __attribute__((ext_vector_type(4))) float f32x4;

static constexpr float PATH_NORM_C = 0.15811388300841897f; // 1/sqrt(40)
static constexpr float CG_C        = 0.57735026918962576f; // 1/sqrt(3)

__device__ __forceinline__ uint32_t f2bf(float f) {
    uint32_t x = __float_as_uint(f);
    return (x + 0x7fffu + ((x >> 16) & 1u)) >> 16;   // RNE, no NaN handling (inputs normal)
}
__device__ __forceinline__ uint32_t pack2(float a, float b) {
    return f2bf(a) | (f2bf(b) << 16);
}

// ---- pre-pass: transpose + bf16-convert the MLP weights -------------------
// W1T[k][j] = fc_w1[j][k]   (64x64)
// W2T[j][k] = fc_w2[k][j]   (1600x64)
__global__ __launch_bounds__(256) void prep_kernel(
    const float* __restrict__ fc_w1, const float* __restrict__ fc_w2,
    ushort* __restrict__ W1T, ushort* __restrict__ W2T)
{
    int i = blockIdx.x * 256 + threadIdx.x;
    if (i < 64 * 64) {
        int k = i >> 6, j = i & 63;
        W1T[k * 64 + j] = (ushort)f2bf(fc_w1[j * 64 + k]);
    }
    int i2 = i - 64 * 64;
    if (i2 >= 0 && i2 < WN * 64) {
        int j = i2 >> 6, k = i2 & 63;
        W2T[j * 64 + k] = (ushort)f2bf(fc_w2[k * WN + j]);
    }
}

__global__ __launch_bounds__(256) void edge_kernel(
    const float* __restrict__ node_attr,
    const float* __restrict__ edge_attr,
    const float* __restrict__ edge_sh,
    const float* __restrict__ fc_b1,
    const float* __restrict__ fc_b2,
    const int*   __restrict__ edge_index,
    const ushort* __restrict__ W1T,
    const ushort* __restrict__ W2T,
    float* __restrict__ acc,
    float* __restrict__ cnt)
{
    // cf rows: 0..31 x0[u]; 32..55 s0*x1[u][m] (32+3u+m); 56..63 y1[u]=CG*(x1.s1);
    //          64 s0; 65..67 s1xyz
    __shared__ float  cf[68][EPB];
    __shared__ int    src_lds[EPB];
    __shared__ ushort hbuf[4][2][1024];  // [wave][msub][(kg*16+q)*8 + ii] bf16 h

    const int tid  = threadIdx.x;
    const int wave = tid >> 6;
    const int lane = tid & 63;
    const int g    = lane >> 4;
    const int q    = lane & 15;
    const int E0   = blockIdx.x * EPB;

    // ---------------- preamble: per-edge coefficient table -------------------
    if (tid < EPB) {
        const int e    = tid;
        const int srcn = edge_index[E0 + e];
        const int dstn = edge_index[NE + E0 + e];
        src_lds[e] = srcn;
        const float4 sh = reinterpret_cast<const float4*>(edge_sh)[E0 + e];
        const float4* xp = reinterpret_cast<const float4*>(node_attr + (size_t)dstn * IND);
        float xr[56];
        #pragma unroll
        for (int i = 0; i < 14; ++i) {
            float4 v = xp[i];
            xr[4*i] = v.x; xr[4*i+1] = v.y; xr[4*i+2] = v.z; xr[4*i+3] = v.w;
        }
        #pragma unroll
        for (int u = 0; u < 32; ++u) cf[u][e] = xr[u];
        #pragma unroll
        for (int u = 0; u < 8; ++u) {
            cf[32 + 3*u + 0][e] = sh.x * xr[32 + 3*u + 0];
            cf[32 + 3*u + 1][e] = sh.x * xr[32 + 3*u + 1];
            cf[32 + 3*u + 2][e] = sh.x * xr[32 + 3*u + 2];
            cf[56 + u][e] = CG_C * (xr[32+3*u]*sh.y + xr[32+3*u+1]*sh.z + xr[32+3*u+2]*sh.w);
        }
        cf[64][e] = sh.x;
        cf[65][e] = sh.y;  cf[66][e] = sh.z;  cf[67][e] = sh.w;
    }

    // ---------------- GEMM1 via transposed MFMA: h_pre[k][e] -----------------
    // D1 = W1T(A: m=k, K=j) * edge_attr^T(B: K=j, n=e)
    f32x4 d1[2][4];   // [msub][mt]
    #pragma unroll
    for (int ms = 0; ms < 2; ++ms)
        #pragma unroll
        for (int mt = 0; mt < 4; ++mt) d1[ms][mt] = (f32x4){0.f, 0.f, 0.f, 0.f};

    #pragma unroll
    for (int kh = 0; kh < 2; ++kh) {
        bf16x8 bfr[2];
        #pragma unroll
        for (int ms = 0; ms < 2; ++ms) {
            const int e = E0 + wave*32 + ms*16 + q;
            const float* ap = edge_attr + (size_t)e * 64 + kh*32 + g*8;
            float4 f0 = *reinterpret_cast<const float4*>(ap);
            float4 f1 = *reinterpret_cast<const float4*>(ap + 4);
            union { uint32_t u[4]; bf16x8 v; } cv;
            cv.u[0] = pack2(f0.x, f0.y); cv.u[1] = pack2(f0.z, f0.w);
            cv.u[2] = pack2(f1.x, f1.y); cv.u[3] = pack2(f1.z, f1.w);
            bfr[ms] = cv.v;
        }
        #pragma unroll
        for (int mt = 0; mt < 4; ++mt) {
            bf16x8 afr = *reinterpret_cast<const bf16x8*>(W1T + (mt*16 + q)*64 + kh*32 + g*8);
            #pragma unroll
            for (int ms = 0; ms < 2; ++ms)
                d1[ms][mt] = __builtin_amdgcn_mfma_f32_16x16x32_bf16(afr, bfr[ms], d1[ms][mt], 0, 0, 0);
        }
    }
    // bias + relu + bf16 pack into per-wave hbuf (a-frag layout for GEMM2)
    #pragma unroll
    for (int mt = 0; mt < 4; ++mt) {
        const float4 b1v = *reinterpret_cast<const float4*>(fc_b1 + mt*16 + 4*g);
        const int kg = 2*mt + (g >> 1);
        #pragma unroll
        for (int ms = 0; ms < 2; ++ms) {
            float v0 = fmaxf(d1[ms][mt][0] + b1v.x, 0.f);
            float v1 = fmaxf(d1[ms][mt][1] + b1v.y, 0.f);
            float v2 = fmaxf(d1[ms][mt][2] + b1v.z, 0.f);
            float v3 = fmaxf(d1[ms][mt][3] + b1v.w, 0.f);
            uint32_t* wp = reinterpret_cast<uint32_t*>(
                &hbuf[wave][ms][(kg*16 + q)*8 + 4*(g & 1)]);
            wp[0] = pack2(v0, v1);
            wp[1] = pack2(v2, v3);
        }
    }

    __syncthreads();

    // GEMM2 A-fragments (h in bf16): lane q = e, k = kh*32 + g*8 + i
    bf16x8 af[2][2]; // [msub][kh]
    #pragma unroll
    for (int ms = 0; ms < 2; ++ms)
        #pragma unroll
        for (int kh = 0; kh < 2; ++kh)
            af[ms][kh] = *reinterpret_cast<const bf16x8*>(
                &hbuf[wave][ms][((kh*4 + g)*16 + q)*8]);

    const int ebase = wave*32 + 4*g;
    f32x4 s0v[2];
    s0v[0] = *reinterpret_cast<const f32x4*>(&cf[64][ebase]);
    s0v[1] = *reinterpret_cast<const f32x4*>(&cf[64][ebase + 16]);

    float o0[2][2][4];   // [msub][vc][r]
    float ttv[2][4];
    float o1v[2][4][3];
    #pragma unroll
    for (int ms = 0; ms < 2; ++ms) {
        #pragma unroll
        for (int r = 0; r < 4; ++r) {
            o0[ms][0][r] = 0.f; o0[ms][1][r] = 0.f; ttv[ms][r] = 0.f;
            o1v[ms][r][0] = 0.f; o1v[ms][r][1] = 0.f; o1v[ms][r][2] = 0.f;
        }
    }

    auto mfma_tile = [&](int t, f32x4* accv) {
        const ushort* p = W2T + (size_t)(t*16 + q) * 64 + g*8;
        bf16x8 b0 = *reinterpret_cast<const bf16x8*>(p);
        bf16x8 b1 = *reinterpret_cast<const bf16x8*>(p + 32);
        #pragma unroll
        for (int ms = 0; ms < 2; ++ms) {
            f32x4 a = (f32x4){0.f, 0.f, 0.f, 0.f};
            a = __builtin_amdgcn_mfma_f32_16x16x32_bf16(af[ms][0], b0, a, 0, 0, 0);
            a = __builtin_amdgcn_mfma_f32_16x16x32_bf16(af[ms][1], b1, a, 0, 0, 0);
            accv[ms] = a;
        }
    };

    // ---- region 1: t 0..63, j=u*32+v, coef s0*x0[u], out0 -------------------
    #pragma unroll 2
    for (int u = 0; u < 32; ++u) {
        f32x4 cfv0 = *reinterpret_cast<const f32x4*>(&cf[u][ebase]);
        f32x4 cfv1 = *reinterpret_cast<const f32x4*>(&cf[u][ebase + 16]);
        #pragma unroll
        for (int vc = 0; vc < 2; ++vc) {
            const int t = 2*u + vc;
            f32x4 w2acc[2];
            mfma_tile(t, w2acc);
            const float b2v = fc_b2[t*16 + q];
            #pragma unroll
            for (int r = 0; r < 4; ++r) {
                o0[0][vc][r] = fmaf(s0v[0][r]*cfv0[r], w2acc[0][r] + b2v, o0[0][vc][r]);
                o0[1][vc][r] = fmaf(s0v[1][r]*cfv1[r], w2acc[1][r] + b2v, o0[1][vc][r]);
            }
        }
    }

    const int qh = q >> 3;

    // ---- region 2: t 64..79, j=1024+u*8+v, coef x0[u], tt -------------------
    #pragma unroll 2
    for (int t2 = 0; t2 < 16; ++t2) {
        const int t = 64 + t2;
        f32x4 w2acc[2];
        mfma_tile(t, w2acc);
        const float b2v = fc_b2[t*16 + q];
        const int u = t2*2 + qh;
        #pragma unroll
        for (int ms = 0; ms < 2; ++ms) {
            f32x4 cfv = *reinterpret_cast<const f32x4*>(&cf[u][ebase + ms*16]);
            #pragma unroll
            for (int r = 0; r < 4; ++r)
                ttv[ms][r] = fmaf(cfv[r], w2acc[ms][r] + b2v, ttv[ms][r]);
        }
    }

    // ---- region 3: t 80..83, j=1280+u*8+v, coef s0*x1[u][m], o1 -------------
    #pragma unroll 2
    for (int t3 = 0; t3 < 4; ++t3) {
        const int t = 80 + t3;
        f32x4 w2acc[2];
        mfma_tile(t, w2acc);
        const float b2v = fc_b2[t*16 + q];
        const int u = t3*2 + qh;
        #pragma unroll
        for (int ms = 0; ms < 2; ++ms) {
            float wv[4];
            #pragma unroll
            for (int r = 0; r < 4; ++r) wv[r] = w2acc[ms][r] + b2v;
            #pragma unroll
            for (int m = 0; m < 3; ++m) {
                f32x4 cfv = *reinterpret_cast<const f32x4*>(&cf[32 + u*3 + m][ebase + ms*16]);
                #pragma unroll
                for (int r = 0; r < 4; ++r)
                    o1v[ms][r][m] = fmaf(cfv[r], wv[r], o1v[ms][r][m]);
            }
        }
    }

    // ---- region 4: t 84..99, j=1344+u*32+v, coef y1[u], out0 ----------------
    #pragma unroll 2
    for (int u4 = 0; u4 < 8; ++u4) {
        f32x4 cfv0 = *reinterpret_cast<const f32x4*>(&cf[56 + u4][ebase]);
        f32x4 cfv1 = *reinterpret_cast<const f32x4*>(&cf[56 + u4][ebase + 16]);
        #pragma unroll
        for (int vc = 0; vc < 2; ++vc) {
            const int t = 84 + 2*u4 + vc;
            f32x4 w2acc[2];
            mfma_tile(t, w2acc);
            const float b2v = fc_b2[t*16 + q];
            #pragma unroll
            for (int r = 0; r < 4; ++r) {
                o0[0][vc][r] = fmaf(cfv0[r], w2acc[0][r] + b2v, o0[0][vc][r]);
                o0[1][vc][r] = fmaf(cfv1[r], w2acc[1][r] + b2v, o0[1][vc][r]);
            }
        }
    }

    // ---- finish: reduce u-halves (lane ^ 8), atomics ------------------------
    #pragma unroll
    for (int ms = 0; ms < 2; ++ms)
        #pragma unroll
        for (int r = 0; r < 4; ++r) {
            ttv[ms][r] += __shfl_xor(ttv[ms][r], 8, 64);
            #pragma unroll
            for (int m = 0; m < 3; ++m)
                o1v[ms][r][m] += __shfl_xor(o1v[ms][r][m], 8, 64);
        }

    #pragma unroll
    for (int ms = 0; ms < 2; ++ms) {
        const int eb = ebase + ms*16;
        const int4 srcv = *reinterpret_cast<const int4*>(&src_lds[eb]);
        const f32x4 s1x = *reinterpret_cast<const f32x4*>(&cf[65][eb]);
        const f32x4 s1y = *reinterpret_cast<const f32x4*>(&cf[66][eb]);
        const f32x4 s1z = *reinterpret_cast<const f32x4*>(&cf[67][eb]);
        #pragma unroll
        for (int r = 0; r < 4; ++r) {
            const int node = (r == 0) ? srcv.x : (r == 1) ? srcv.y : (r == 2) ? srcv.z : srcv.w;
            float* ap = acc + (size_t)node * IND;
            atomicAdd(ap + q,      PATH_NORM_C * o0[ms][0][r]);
            atomicAdd(ap + 16 + q, PATH_NORM_C * o0[ms][1][r]);
            if ((q & 8) == 0) {
                const int v = q & 7;
                atomicAdd(ap + 32 + 3*v + 0, PATH_NORM_C * (o1v[ms][r][0] + s1x[r]*ttv[ms][r]));
                atomicAdd(ap + 32 + 3*v + 1, PATH_NORM_C * (o1v[ms][r][1] + s1y[r]*ttv[ms][r]));
                atomicAdd(ap + 32 + 3*v + 2, PATH_NORM_C * (o1v[ms][r][2] + s1z[r]*ttv[ms][r]));
            }
        }
    }

    if (lane < 32) atomicAdd(cnt + src_lds[wave*32 + lane], 1.0f);
}

__global__ __launch_bounds__(256) void finalize_kernel(
    const float* __restrict__ acc, const float* __restrict__ cnt,
    const float* __restrict__ node_attr, float* __restrict__ out)
{
    const int i = blockIdx.x * 256 + threadIdx.x;
    if (i >= NN * IND) return;
    const int n = i / IND;
    const float c = fmaxf(cnt[n], 1.0f);
    out[i] = acc[i] / c + node_attr[i];
}

extern "C" void kernel_launch(void* const* d_in, const int* in_sizes, int n_in,
                              void* d_out, int out_size, void* d_ws, size_t ws_size,
                              hipStream_t stream) {
    const float* node_attr = (const float*)d_in[0];
    const float* edge_attr = (const float*)d_in[1];
    const float* edge_sh   = (const float*)d_in[2];
    const float* fc_w1     = (const float*)d_in[3];
    const float* fc_b1     = (const float*)d_in[4];
    const float* fc_w2     = (const float*)d_in[5];
    const float* fc_b2     = (const float*)d_in[6];
    const int*   edge_index = (const int*)d_in[7];

    float* acc = (float*)d_ws;
    float* cnt = acc + (size_t)NN * IND;
    // bf16 weight tables after acc+cnt (2,280,000 B, 16B-aligned)
    ushort* W1T = (ushort*)((char*)d_ws + 2280000);
    ushort* W2T = W1T + 64 * 64;

    hipMemsetAsync(d_ws, 0, ((size_t)NN * IND + NN) * sizeof(float), stream);

    prep_kernel<<<(64*64 + WN*64 + 255) / 256, 256, 0, stream>>>(fc_w1, fc_w2, W1T, W2T);

    edge_kernel<<<NBLK, 256, 0, stream>>>(
        node_attr, edge_attr, edge_sh, fc_b1, fc_b2, edge_index, W1T, W2T, acc, cnt);

    finalize_kernel<<<(NN * IND + 255) / 256, 256, 0, stream>>>(
        acc, cnt, node_attr, (float*)d_out);
}

// Round 4
// 209.463 us; speedup vs baseline: 7.9015x; 1.0318x over previous
//
#include <hip/hip_runtime.h>

#define NN 10000
#define NE 160000
#define IND 56          // 32 + 3*8
#define WN 1600
#define EPB 128         // edges per block (4 waves x 32)
#define NBLK (NE / EPB) // 1250

typedef __attribute__((ext_vector_type(8))) short bf16x8;
typedef __attribute__((ext_vector_type(4))) float f32x4;

static constexpr float PATH_NORM_C = 0.15811388300841897f; // 1/sqrt(40)
static constexpr float CG_C        = 0.57735026918962576f; // 1/sqrt(3)

__device__ __forceinline__ uint32_t f2bf(float f) {
    uint32_t x = __float_as_uint(f);
    return (x + 0x7fffu + ((x >> 16) & 1u)) >> 16;   // RNE
}
__device__ __forceinline__ uint32_t pack2(float a, float b) {
    return f2bf(a) | (f2bf(b) << 16);
}

// ---- pre-pass: transpose + bf16-convert the MLP weights -------------------
__global__ __launch_bounds__(256) void prep_kernel(
    const float* __restrict__ fc_w1, const float* __restrict__ fc_w2,
    ushort* __restrict__ W1T, ushort* __restrict__ W2T)
{
    int i = blockIdx.x * 256 + threadIdx.x;
    if (i < 64 * 64) {
        int k = i >> 6, j = i & 63;
        W1T[k * 64 + j] = (ushort)f2bf(fc_w1[j * 64 + k]);
    }
    int i2 = i - 64 * 64;
    if (i2 >= 0 && i2 < WN * 64) {
        int j = i2 >> 6, k = i2 & 63;
        W2T[j * 64 + k] = (ushort)f2bf(fc_w2[k * WN + j]);
    }
}

__global__ __launch_bounds__(256) void edge_kernel(
    const float* __restrict__ node_attr,
    const float* __restrict__ edge_attr,
    const float* __restrict__ edge_sh,
    const float* __restrict__ fc_b1,
    const float* __restrict__ fc_b2,
    const int*   __restrict__ edge_index,
    const ushort* __restrict__ W1T,
    const ushort* __restrict__ W2T,
    float* __restrict__ acc,
    float* __restrict__ cnt)
{
    // cf rows: 0..31 x0[u]; 32..55 s0*x1[u][m]; 56..63 y1[u]; 64 s0; 65..67 s1
    __shared__ float  cf[68][EPB];
    __shared__ int    src_lds[EPB];
    __shared__ ushort hbuf[4][2][1024];

    const int tid  = threadIdx.x;
    const int wave = tid >> 6;
    const int lane = tid & 63;
    const int g    = lane >> 4;
    const int q    = lane & 15;
    const int E0   = blockIdx.x * EPB;

    // ---------------- preamble: per-edge coefficient table -------------------
    if (tid < EPB) {
        const int e    = tid;
        const int srcn = edge_index[E0 + e];
        const int dstn = edge_index[NE + E0 + e];
        src_lds[e] = srcn;
        const float4 sh = reinterpret_cast<const float4*>(edge_sh)[E0 + e];
        const float4* xp = reinterpret_cast<const float4*>(node_attr + (size_t)dstn * IND);
        float xr[56];
        #pragma unroll
        for (int i = 0; i < 14; ++i) {
            float4 v = xp[i];
            xr[4*i] = v.x; xr[4*i+1] = v.y; xr[4*i+2] = v.z; xr[4*i+3] = v.w;
        }
        #pragma unroll
        for (int u = 0; u < 32; ++u) cf[u][e] = xr[u];
        #pragma unroll
        for (int u = 0; u < 8; ++u) {
            cf[32 + 3*u + 0][e] = sh.x * xr[32 + 3*u + 0];
            cf[32 + 3*u + 1][e] = sh.x * xr[32 + 3*u + 1];
            cf[32 + 3*u + 2][e] = sh.x * xr[32 + 3*u + 2];
            cf[56 + u][e] = CG_C * (xr[32+3*u]*sh.y + xr[32+3*u+1]*sh.z + xr[32+3*u+2]*sh.w);
        }
        cf[64][e] = sh.x;
        cf[65][e] = sh.y;  cf[66][e] = sh.z;  cf[67][e] = sh.w;
    }

    // ---------------- GEMM1 via transposed MFMA: h_pre[k][e] -----------------
    f32x4 d1[2][4];   // [msub][mt], init = fc_b1 broadcast (row = k-index)
    #pragma unroll
    for (int mt = 0; mt < 4; ++mt) {
        const float4 b1v = *reinterpret_cast<const float4*>(fc_b1 + mt*16 + 4*g);
        #pragma unroll
        for (int ms = 0; ms < 2; ++ms)
            d1[ms][mt] = (f32x4){b1v.x, b1v.y, b1v.z, b1v.w};
    }

    #pragma unroll
    for (int kh = 0; kh < 2; ++kh) {
        bf16x8 bfr[2];
        #pragma unroll
        for (int ms = 0; ms < 2; ++ms) {
            const int e = E0 + wave*32 + ms*16 + q;
            const float* ap = edge_attr + (size_t)e * 64 + kh*32 + g*8;
            float4 f0 = *reinterpret_cast<const float4*>(ap);
            float4 f1 = *reinterpret_cast<const float4*>(ap + 4);
            union { uint32_t u[4]; bf16x8 v; } cv;
            cv.u[0] = pack2(f0.x, f0.y); cv.u[1] = pack2(f0.z, f0.w);
            cv.u[2] = pack2(f1.x, f1.y); cv.u[3] = pack2(f1.z, f1.w);
            bfr[ms] = cv.v;
        }
        #pragma unroll
        for (int mt = 0; mt < 4; ++mt) {
            bf16x8 afr = *reinterpret_cast<const bf16x8*>(W1T + (mt*16 + q)*64 + kh*32 + g*8);
            #pragma unroll
            for (int ms = 0; ms < 2; ++ms)
                d1[ms][mt] = __builtin_amdgcn_mfma_f32_16x16x32_bf16(afr, bfr[ms], d1[ms][mt], 0, 0, 0);
        }
    }
    // relu + bf16 pack into per-wave hbuf (a-frag layout for GEMM2)
    #pragma unroll
    for (int mt = 0; mt < 4; ++mt) {
        const int kg = 2*mt + (g >> 1);
        #pragma unroll
        for (int ms = 0; ms < 2; ++ms) {
            float v0 = fmaxf(d1[ms][mt][0], 0.f);
            float v1 = fmaxf(d1[ms][mt][1], 0.f);
            float v2 = fmaxf(d1[ms][mt][2], 0.f);
            float v3 = fmaxf(d1[ms][mt][3], 0.f);
            uint32_t* wp = reinterpret_cast<uint32_t*>(
                &hbuf[wave][ms][(kg*16 + q)*8 + 4*(g & 1)]);
            wp[0] = pack2(v0, v1);
            wp[1] = pack2(v2, v3);
        }
    }

    // prefetch slots for the W2T tile stream (issue tiles 0,1 before barrier)
    bf16x8 A0, A1, B0, B1;
    float  Ab, Bb;
    auto load_tile = [&](int t, bf16x8& b0, bf16x8& b1, float& b2v) {
        const ushort* p = W2T + (size_t)(t*16 + q) * 64 + g*8;
        b0 = *reinterpret_cast<const bf16x8*>(p);
        b1 = *reinterpret_cast<const bf16x8*>(p + 32);
        b2v = fc_b2[t*16 + q];
    };
    load_tile(0, A0, A1, Ab);
    load_tile(1, B0, B1, Bb);

    __syncthreads();

    // GEMM2 A-fragments (h in bf16): lane q = e, k = kh*32 + g*8 + i
    bf16x8 af[2][2];
    #pragma unroll
    for (int ms = 0; ms < 2; ++ms)
        #pragma unroll
        for (int kh = 0; kh < 2; ++kh)
            af[ms][kh] = *reinterpret_cast<const bf16x8*>(
                &hbuf[wave][ms][((kh*4 + g)*16 + q)*8]);

    const int ebase = wave*32 + 4*g;
    f32x4 s0v[2];
    s0v[0] = *reinterpret_cast<const f32x4*>(&cf[64][ebase]);
    s0v[1] = *reinterpret_cast<const f32x4*>(&cf[64][ebase + 16]);

    float o0[2][2][4];
    float ttv[2][4];
    float o1v[2][4][3];
    #pragma unroll
    for (int ms = 0; ms < 2; ++ms) {
        #pragma unroll
        for (int r = 0; r < 4; ++r) {
            o0[ms][0][r] = 0.f; o0[ms][1][r] = 0.f; ttv[ms][r] = 0.f;
            o1v[ms][r][0] = 0.f; o1v[ms][r][1] = 0.f; o1v[ms][r][2] = 0.f;
        }
    }

    // bias folded into accumulator init (C-in = b2v on all rows)
    auto mfma2 = [&](const bf16x8& b0, const bf16x8& b1, float b2v, f32x4* accv) {
        #pragma unroll
        for (int ms = 0; ms < 2; ++ms) {
            f32x4 a = (f32x4){b2v, b2v, b2v, b2v};
            a = __builtin_amdgcn_mfma_f32_16x16x32_bf16(af[ms][0], b0, a, 0, 0, 0);
            a = __builtin_amdgcn_mfma_f32_16x16x32_bf16(af[ms][1], b1, a, 0, 0, 0);
            accv[ms] = a;
        }
    };

    int pt = 2;   // next tile to prefetch (uniform)
    const int qh = q >> 3;

    // ---- region 1: tiles 0..63 (u-major, vc = tile&1), coef s0*x0[u] --------
    #pragma unroll 1
    for (int u = 0; u < 32; ++u) {
        f32x4 cfv0 = *reinterpret_cast<const f32x4*>(&cf[u][ebase]);
        f32x4 cfv1 = *reinterpret_cast<const f32x4*>(&cf[u][ebase + 16]);
        f32x4 w2acc[2];
        mfma2(A0, A1, Ab, w2acc);
        load_tile(pt < 99 ? pt : 99, A0, A1, Ab); ++pt;
        #pragma unroll
        for (int r = 0; r < 4; ++r) {
            o0[0][0][r] = fmaf(s0v[0][r]*cfv0[r], w2acc[0][r], o0[0][0][r]);
            o0[1][0][r] = fmaf(s0v[1][r]*cfv1[r], w2acc[1][r], o0[1][0][r]);
        }
        mfma2(B0, B1, Bb, w2acc);
        load_tile(pt < 99 ? pt : 99, B0, B1, Bb); ++pt;
        #pragma unroll
        for (int r = 0; r < 4; ++r) {
            o0[0][1][r] = fmaf(s0v[0][r]*cfv0[r], w2acc[0][r], o0[0][1][r]);
            o0[1][1][r] = fmaf(s0v[1][r]*cfv1[r], w2acc[1][r], o0[1][1][r]);
        }
    }

    // ---- region 2: tiles 64..79, u = 2*t2 + qh, coef x0[u] ------------------
    #pragma unroll 1
    for (int t2 = 0; t2 < 16; t2 += 2) {
        f32x4 w2acc[2];
        mfma2(A0, A1, Ab, w2acc);
        load_tile(pt < 99 ? pt : 99, A0, A1, Ab); ++pt;
        {
            const int u = 2*t2 + qh;
            #pragma unroll
            for (int ms = 0; ms < 2; ++ms) {
                f32x4 cfv = *reinterpret_cast<const f32x4*>(&cf[u][ebase + ms*16]);
                #pragma unroll
                for (int r = 0; r < 4; ++r)
                    ttv[ms][r] = fmaf(cfv[r], w2acc[ms][r], ttv[ms][r]);
            }
        }
        mfma2(B0, B1, Bb, w2acc);
        load_tile(pt < 99 ? pt : 99, B0, B1, Bb); ++pt;
        {
            const int u = 2*(t2+1) + qh;
            #pragma unroll
            for (int ms = 0; ms < 2; ++ms) {
                f32x4 cfv = *reinterpret_cast<const f32x4*>(&cf[u][ebase + ms*16]);
                #pragma unroll
                for (int r = 0; r < 4; ++r)
                    ttv[ms][r] = fmaf(cfv[r], w2acc[ms][r], ttv[ms][r]);
            }
        }
    }

    // ---- region 3: tiles 80..83, u = 2*t3 + qh, coef s0*x1[u][m] ------------
    #pragma unroll 1
    for (int t3 = 0; t3 < 4; t3 += 2) {
        f32x4 w2acc[2];
        mfma2(A0, A1, Ab, w2acc);
        load_tile(pt < 99 ? pt : 99, A0, A1, Ab); ++pt;
        {
            const int u = 2*t3 + qh;
            #pragma unroll
            for (int ms = 0; ms < 2; ++ms)
                #pragma unroll
                for (int m = 0; m < 3; ++m) {
                    f32x4 cfv = *reinterpret_cast<const f32x4*>(&cf[32 + u*3 + m][ebase + ms*16]);
                    #pragma unroll
                    for (int r = 0; r < 4; ++r)
                        o1v[ms][r][m] = fmaf(cfv[r], w2acc[ms][r], o1v[ms][r][m]);
                }
        }
        mfma2(B0, B1, Bb, w2acc);
        load_tile(pt < 99 ? pt : 99, B0, B1, Bb); ++pt;
        {
            const int u = 2*(t3+1) + qh;
            #pragma unroll
            for (int ms = 0; ms < 2; ++ms)
                #pragma unroll
                for (int m = 0; m < 3; ++m) {
                    f32x4 cfv = *reinterpret_cast<const f32x4*>(&cf[32 + u*3 + m][ebase + ms*16]);
                    #pragma unroll
                    for (int r = 0; r < 4; ++r)
                        o1v[ms][r][m] = fmaf(cfv[r], w2acc[ms][r], o1v[ms][r][m]);
                }
        }
    }

    // ---- region 4: tiles 84..99, coef y1[u4] --------------------------------
    #pragma unroll 1
    for (int u4 = 0; u4 < 8; ++u4) {
        f32x4 cfv0 = *reinterpret_cast<const f32x4*>(&cf[56 + u4][ebase]);
        f32x4 cfv1 = *reinterpret_cast<const f32x4*>(&cf[56 + u4][ebase + 16]);
        f32x4 w2acc[2];
        mfma2(A0, A1, Ab, w2acc);
        load_tile(pt < 99 ? pt : 99, A0, A1, Ab); ++pt;
        #pragma unroll
        for (int r = 0; r < 4; ++r) {
            o0[0][0][r] = fmaf(cfv0[r], w2acc[0][r], o0[0][0][r]);
            o0[1][0][r] = fmaf(cfv1[r], w2acc[1][r], o0[1][0][r]);
        }
        mfma2(B0, B1, Bb, w2acc);
        load_tile(pt < 99 ? pt : 99, B0, B1, Bb); ++pt;
        #pragma unroll
        for (int r = 0; r < 4; ++r) {
            o0[0][1][r] = fmaf(cfv0[r], w2acc[0][r], o0[0][1][r]);
            o0[1][1][r] = fmaf(cfv1[r], w2acc[1][r], o0[1][1][r]);
        }
    }

    // ---- finish: reduce u-halves (lane ^ 8), atomics ------------------------
    #pragma unroll
    for (int ms = 0; ms < 2; ++ms)
        #pragma unroll
        for (int r = 0; r < 4; ++r) {
            ttv[ms][r] += __shfl_xor(ttv[ms][r], 8, 64);
            #pragma unroll
            for (int m = 0; m < 3; ++m)
                o1v[ms][r][m] += __shfl_xor(o1v[ms][r][m], 8, 64);
        }

    #pragma unroll
    for (int ms = 0; ms < 2; ++ms) {
        const int eb = ebase + ms*16;
        const int4 srcv = *reinterpret_cast<const int4*>(&src_lds[eb]);
        const f32x4 s1x = *reinterpret_cast<const f32x4*>(&cf[65][eb]);
        const f32x4 s1y = *reinterpret_cast<const f32x4*>(&cf[66][eb]);
        const f32x4 s1z = *reinterpret_cast<const f32x4*>(&cf[67][eb]);
        #pragma unroll
        for (int r = 0; r < 4; ++r) {
            const int node = (r == 0) ? srcv.x : (r == 1) ? srcv.y : (r == 2) ? srcv.z : srcv.w;
            float* ap = acc + (size_t)node * IND;
            atomicAdd(ap + q,      PATH_NORM_C * o0[ms][0][r]);
            atomicAdd(ap + 16 + q, PATH_NORM_C * o0[ms][1][r]);
            if ((q & 8) == 0) {
                const int v = q & 7;
                atomicAdd(ap + 32 + 3*v + 0, PATH_NORM_C * (o1v[ms][r][0] + s1x[r]*ttv[ms][r]));
                atomicAdd(ap + 32 + 3*v + 1, PATH_NORM_C * (o1v[ms][r][1] + s1y[r]*ttv[ms][r]));
                atomicAdd(ap + 32 + 3*v + 2, PATH_NORM_C * (o1v[ms][r][2] + s1z[r]*ttv[ms][r]));
            }
        }
    }

    if (lane < 32) atomicAdd(cnt + src_lds[wave*32 + lane], 1.0f);
}

__global__ __launch_bounds__(256) void finalize_kernel(
    const float* __restrict__ acc, const float* __restrict__ cnt,
    const float* __restrict__ node_attr, float* __restrict__ out)
{
    const int i = blockIdx.x * 256 + threadIdx.x;
    if (i >= NN * IND) return;
    const int n = i / IND;
    const float c = fmaxf(cnt[n], 1.0f);
    out[i] = acc[i] / c + node_attr[i];
}

extern "C" void kernel_launch(void* const* d_in, const int* in_sizes, int n_in,
                              void* d_out, int out_size, void* d_ws, size_t ws_size,
                              hipStream_t stream) {
    const float* node_attr = (const float*)d_in[0];
    const float* edge_attr = (const float*)d_in[1];
    const float* edge_sh   = (const float*)d_in[2];
    const float* fc_w1     = (const float*)d_in[3];
    const float* fc_b1     = (const float*)d_in[4];
    const float* fc_w2     = (const float*)d_in[5];
    const float* fc_b2     = (const float*)d_in[6];
    const int*   edge_index = (const int*)d_in[7];

    float* acc = (float*)d_ws;
    float* cnt = acc + (size_t)NN * IND;
    ushort* W1T = (ushort*)((char*)d_ws + 2280000);
    ushort* W2T = W1T + 64 * 64;

    hipMemsetAsync(d_ws, 0, ((size_t)NN * IND + NN) * sizeof(float), stream);

    prep_kernel<<<(64*64 + WN*64 + 255) / 256, 256, 0, stream>>>(fc_w1, fc_w2, W1T, W2T);

    edge_kernel<<<NBLK, 256, 0, stream>>>(
        node_attr, edge_attr, edge_sh, fc_b1, fc_b2, edge_index, W1T, W2T, acc, cnt);

    finalize_kernel<<<(NN * IND + 255) / 256, 256, 0, stream>>>(
        acc, cnt, node_attr, (float*)d_out);
}

// Round 5
// 183.026 us; speedup vs baseline: 9.0429x; 1.1444x over previous
//
#include <hip/hip_runtime.h>

#define NN 10000
#define NE 160000
#define IND 56          // 32 + 3*8
#define WN 1600
#define EPB 128         // edges per block (4 waves x 32)
#define NBLK (NE / EPB) // 1250

typedef __attribute__((ext_vector_type(8))) short bf16x8;
typedef __attribute__((ext_vector_type(4))) float f32x4;

static constexpr float PATH_NORM_C = 0.15811388300841897f; // 1/sqrt(40)
static constexpr float CG_C        = 0.57735026918962576f; // 1/sqrt(3)

__device__ __forceinline__ uint32_t f2bf(float f) {
    uint32_t x = __float_as_uint(f);
    return (x + 0x7fffu + ((x >> 16) & 1u)) >> 16;   // RNE
}
__device__ __forceinline__ uint32_t pack2(float a, float b) {
    return f2bf(a) | (f2bf(b) << 16);
}

// ---- pre-pass: W1T (GEMM1 A-source) + W2F (GEMM2 B in fragment order) ------
// W1T[k][j] = fc_w1[j][k]  (64x64 bf16)
// W2F[t*1024 + kh*512 + l*8 + i] = fc_w2[k*WN + j],
//   j = t*16 + (l&15), k = kh*32 + (l>>4)*8 + i   -> per-tile loads contiguous
__global__ __launch_bounds__(256) void prep_kernel(
    const float* __restrict__ fc_w1, const float* __restrict__ fc_w2,
    ushort* __restrict__ W1T, ushort* __restrict__ W2F)
{
    int i = blockIdx.x * 256 + threadIdx.x;
    if (i < 64 * 64) {
        int k = i >> 6, j = i & 63;
        W1T[k * 64 + j] = (ushort)f2bf(fc_w1[j * 64 + k]);
    }
    int i2 = i - 64 * 64;
    if (i2 >= 0 && i2 < 100 * 1024) {
        int t  = i2 >> 10, r = i2 & 1023;
        int kh = r >> 9,  rr = r & 511;
        int l  = rr >> 3, ii = rr & 7;
        int j  = t * 16 + (l & 15);
        int k  = kh * 32 + ((l >> 4) << 3) + ii;
        W2F[i2] = (ushort)f2bf(fc_w2[k * WN + j]);
    }
}

__global__ __launch_bounds__(256) void edge_kernel(
    const float* __restrict__ node_attr,
    const float* __restrict__ edge_attr,
    const float* __restrict__ edge_sh,
    const float* __restrict__ fc_b1,
    const float* __restrict__ fc_b2,
    const int*   __restrict__ edge_index,
    const ushort* __restrict__ W1T,
    const ushort* __restrict__ W2F,
    float* __restrict__ acc,
    float* __restrict__ cnt)
{
    // cf rows: 0..31 x0[u]; 32..55 s0*x1[u][m]; 56..63 y1[u]; 64 s0; 65..67 s1
    __shared__ float  cf[68][EPB];
    __shared__ int    src_lds[EPB];
    // pool overlays: phase 1 = hbuf[4 waves][2 ms][1024] ushort (GEMM1->GEMM2 relay)
    //                phase 2 = stage[2 bufs][4096] ushort (8KB W2F chunks, dbuf)
    __shared__ __attribute__((aligned(16))) ushort pool[8192];

    const int tid  = threadIdx.x;
    const int wave = tid >> 6;
    const int lane = tid & 63;
    const int g    = lane >> 4;
    const int q    = lane & 15;
    const int E0   = blockIdx.x * EPB;

    // ---------------- preamble: per-edge coefficient table -------------------
    if (tid < EPB) {
        const int e    = tid;
        const int srcn = edge_index[E0 + e];
        const int dstn = edge_index[NE + E0 + e];
        src_lds[e] = srcn;
        const float4 sh = reinterpret_cast<const float4*>(edge_sh)[E0 + e];
        const float4* xp = reinterpret_cast<const float4*>(node_attr + (size_t)dstn * IND);
        float xr[56];
        #pragma unroll
        for (int i = 0; i < 14; ++i) {
            float4 v = xp[i];
            xr[4*i] = v.x; xr[4*i+1] = v.y; xr[4*i+2] = v.z; xr[4*i+3] = v.w;
        }
        #pragma unroll
        for (int u = 0; u < 32; ++u) cf[u][e] = xr[u];
        #pragma unroll
        for (int u = 0; u < 8; ++u) {
            cf[32 + 3*u + 0][e] = sh.x * xr[32 + 3*u + 0];
            cf[32 + 3*u + 1][e] = sh.x * xr[32 + 3*u + 1];
            cf[32 + 3*u + 2][e] = sh.x * xr[32 + 3*u + 2];
            cf[56 + u][e] = CG_C * (xr[32+3*u]*sh.y + xr[32+3*u+1]*sh.z + xr[32+3*u+2]*sh.w);
        }
        cf[64][e] = sh.x;
        cf[65][e] = sh.y;  cf[66][e] = sh.z;  cf[67][e] = sh.w;
    }

    // ---------------- GEMM1 via transposed MFMA: h_pre[k][e] -----------------
    f32x4 d1[2][4];
    #pragma unroll
    for (int mt = 0; mt < 4; ++mt) {
        const float4 b1v = *reinterpret_cast<const float4*>(fc_b1 + mt*16 + 4*g);
        #pragma unroll
        for (int ms = 0; ms < 2; ++ms)
            d1[ms][mt] = (f32x4){b1v.x, b1v.y, b1v.z, b1v.w};
    }

    #pragma unroll
    for (int kh = 0; kh < 2; ++kh) {
        bf16x8 bfr[2];
        #pragma unroll
        for (int ms = 0; ms < 2; ++ms) {
            const int e = E0 + wave*32 + ms*16 + q;
            const float* ap = edge_attr + (size_t)e * 64 + kh*32 + g*8;
            float4 f0 = *reinterpret_cast<const float4*>(ap);
            float4 f1 = *reinterpret_cast<const float4*>(ap + 4);
            union { uint32_t u[4]; bf16x8 v; } cv;
            cv.u[0] = pack2(f0.x, f0.y); cv.u[1] = pack2(f0.z, f0.w);
            cv.u[2] = pack2(f1.x, f1.y); cv.u[3] = pack2(f1.z, f1.w);
            bfr[ms] = cv.v;
        }
        #pragma unroll
        for (int mt = 0; mt < 4; ++mt) {
            bf16x8 afr = *reinterpret_cast<const bf16x8*>(W1T + (mt*16 + q)*64 + kh*32 + g*8);
            #pragma unroll
            for (int ms = 0; ms < 2; ++ms)
                d1[ms][mt] = __builtin_amdgcn_mfma_f32_16x16x32_bf16(afr, bfr[ms], d1[ms][mt], 0, 0, 0);
        }
    }
    // relu + bf16 pack into own-wave hbuf region of pool
    #pragma unroll
    for (int mt = 0; mt < 4; ++mt) {
        const int kg = 2*mt + (g >> 1);
        #pragma unroll
        for (int ms = 0; ms < 2; ++ms) {
            float v0 = fmaxf(d1[ms][mt][0], 0.f);
            float v1 = fmaxf(d1[ms][mt][1], 0.f);
            float v2 = fmaxf(d1[ms][mt][2], 0.f);
            float v3 = fmaxf(d1[ms][mt][3], 0.f);
            uint32_t* wp = reinterpret_cast<uint32_t*>(
                &pool[wave*2048 + ms*1024 + (kg*16 + q)*8 + 4*(g & 1)]);
            wp[0] = pack2(v0, v1);
            wp[1] = pack2(v2, v3);
        }
    }

    // read own-wave A-fragments back (same-wave ds order via lgkmcnt -> safe)
    bf16x8 af[2][2];
    #pragma unroll
    for (int ms = 0; ms < 2; ++ms)
        #pragma unroll
        for (int kh = 0; kh < 2; ++kh)
            af[ms][kh] = *reinterpret_cast<const bf16x8*>(
                &pool[wave*2048 + ms*1024 + ((kh*4 + g)*16 + q)*8]);

    __syncthreads();   // all waves done with pool-as-hbuf; cf visible to all

    // ---------------- staged GEMM2 + fused TP epilogue -----------------------
    const char* W2Fb = reinterpret_cast<const char*>(W2F);

    auto stage_chunk = [&](int buf, int c) {
        #pragma unroll
        for (int j = 0; j < 2; ++j) {
            const char* gp = W2Fb + (size_t)c*8192 + wave*2048 + j*1024 + lane*16;
            ushort* lp = &pool[buf*4096 + wave*1024 + j*512 + lane*8];
            __builtin_amdgcn_global_load_lds(
                (const __attribute__((address_space(1))) void*)gp,
                (__attribute__((address_space(3))) void*)lp, 16, 0, 0);
        }
    };

    float b2c0, b2c1, b2c2, b2c3, b2n0, b2n1, b2n2, b2n3;
    {
        const float* bp = fc_b2 + q;
        b2c0 = bp[0]; b2c1 = bp[16]; b2c2 = bp[32]; b2c3 = bp[48];
    }
    stage_chunk(0, 0);
    __syncthreads();   // chunk 0 resident

    const int ebase = wave*32 + 4*g;
    f32x4 s0v[2];
    s0v[0] = *reinterpret_cast<const f32x4*>(&cf[64][ebase]);
    s0v[1] = *reinterpret_cast<const f32x4*>(&cf[64][ebase + 16]);

    float o0[2][2][4];
    float ttv[2][4];
    float o1v[2][4][3];
    #pragma unroll
    for (int ms = 0; ms < 2; ++ms) {
        #pragma unroll
        for (int r = 0; r < 4; ++r) {
            o0[ms][0][r] = 0.f; o0[ms][1][r] = 0.f; ttv[ms][r] = 0.f;
            o1v[ms][r][0] = 0.f; o1v[ms][r][1] = 0.f; o1v[ms][r][2] = 0.f;
        }
    }

    auto mfma2 = [&](const bf16x8& b0, const bf16x8& b1, float b2v, f32x4* accv) {
        #pragma unroll
        for (int ms = 0; ms < 2; ++ms) {
            f32x4 a = (f32x4){b2v, b2v, b2v, b2v};
            a = __builtin_amdgcn_mfma_f32_16x16x32_bf16(af[ms][0], b0, a, 0, 0, 0);
            a = __builtin_amdgcn_mfma_f32_16x16x32_bf16(af[ms][1], b1, a, 0, 0, 0);
            accv[ms] = a;
        }
    };

    const int qh = q >> 3;

    #pragma unroll 1
    for (int c = 0; c < 25; ++c) {
        const int cb = c & 1;
        if (c < 24) {
            stage_chunk(cb ^ 1, c + 1);
            const float* bp = fc_b2 + (c + 1)*64 + q;
            b2n0 = bp[0]; b2n1 = bp[16]; b2n2 = bp[32]; b2n3 = bp[48];
        }
        #pragma unroll
        for (int tc = 0; tc < 4; ++tc) {
            const int t = c*4 + tc;
            const float b2v = (tc == 0) ? b2c0 : (tc == 1) ? b2c1 : (tc == 2) ? b2c2 : b2c3;
            bf16x8 b0 = *reinterpret_cast<const bf16x8*>(&pool[cb*4096 + tc*1024 + lane*8]);
            bf16x8 b1 = *reinterpret_cast<const bf16x8*>(&pool[cb*4096 + tc*1024 + 512 + lane*8]);
            f32x4 w2acc[2];
            mfma2(b0, b1, b2v, w2acc);

            if (t < 64) {            // region 1: u = t>>1, vc = tc&1, coef s0*x0[u]
                const int u = t >> 1;
                f32x4 cfv0 = *reinterpret_cast<const f32x4*>(&cf[u][ebase]);
                f32x4 cfv1 = *reinterpret_cast<const f32x4*>(&cf[u][ebase + 16]);
                #pragma unroll
                for (int r = 0; r < 4; ++r) {
                    o0[0][tc & 1][r] = fmaf(s0v[0][r]*cfv0[r], w2acc[0][r], o0[0][tc & 1][r]);
                    o0[1][tc & 1][r] = fmaf(s0v[1][r]*cfv1[r], w2acc[1][r], o0[1][tc & 1][r]);
                }
            } else if (t < 80) {     // region 2: u = 2*(t-64)+qh, coef x0[u]
                const int u = 2*(t - 64) + qh;
                #pragma unroll
                for (int ms = 0; ms < 2; ++ms) {
                    f32x4 cfv = *reinterpret_cast<const f32x4*>(&cf[u][ebase + ms*16]);
                    #pragma unroll
                    for (int r = 0; r < 4; ++r)
                        ttv[ms][r] = fmaf(cfv[r], w2acc[ms][r], ttv[ms][r]);
                }
            } else if (t < 84) {     // region 3: u = 2*(t-80)+qh, coef s0*x1[u][m]
                const int u = 2*(t - 80) + qh;
                #pragma unroll
                for (int ms = 0; ms < 2; ++ms)
                    #pragma unroll
                    for (int m = 0; m < 3; ++m) {
                        f32x4 cfv = *reinterpret_cast<const f32x4*>(&cf[32 + u*3 + m][ebase + ms*16]);
                        #pragma unroll
                        for (int r = 0; r < 4; ++r)
                            o1v[ms][r][m] = fmaf(cfv[r], w2acc[ms][r], o1v[ms][r][m]);
                    }
            } else {                 // region 4: u4 = (t-84)>>1, vc = tc&1, coef y1[u4]
                const int u4 = (t - 84) >> 1;
                f32x4 cfv0 = *reinterpret_cast<const f32x4*>(&cf[56 + u4][ebase]);
                f32x4 cfv1 = *reinterpret_cast<const f32x4*>(&cf[56 + u4][ebase + 16]);
                #pragma unroll
                for (int r = 0; r < 4; ++r) {
                    o0[0][tc & 1][r] = fmaf(cfv0[r], w2acc[0][r], o0[0][tc & 1][r]);
                    o0[1][tc & 1][r] = fmaf(cfv1[r], w2acc[1][r], o0[1][tc & 1][r]);
                }
            }
        }
        __syncthreads();   // stage(c+1) complete; buf cb free for reuse
        b2c0 = b2n0; b2c1 = b2n1; b2c2 = b2n2; b2c3 = b2n3;
    }

    // ---- finish: reduce u-halves (lane ^ 8), atomics ------------------------
    #pragma unroll
    for (int ms = 0; ms < 2; ++ms)
        #pragma unroll
        for (int r = 0; r < 4; ++r) {
            ttv[ms][r] += __shfl_xor(ttv[ms][r], 8, 64);
            #pragma unroll
            for (int m = 0; m < 3; ++m)
                o1v[ms][r][m] += __shfl_xor(o1v[ms][r][m], 8, 64);
        }

    #pragma unroll
    for (int ms = 0; ms < 2; ++ms) {
        const int eb = ebase + ms*16;
        const int4 srcv = *reinterpret_cast<const int4*>(&src_lds[eb]);
        const f32x4 s1x = *reinterpret_cast<const f32x4*>(&cf[65][eb]);
        const f32x4 s1y = *reinterpret_cast<const f32x4*>(&cf[66][eb]);
        const f32x4 s1z = *reinterpret_cast<const f32x4*>(&cf[67][eb]);
        #pragma unroll
        for (int r = 0; r < 4; ++r) {
            const int node = (r == 0) ? srcv.x : (r == 1) ? srcv.y : (r == 2) ? srcv.z : srcv.w;
            float* ap = acc + (size_t)node * IND;
            atomicAdd(ap + q,      PATH_NORM_C * o0[ms][0][r]);
            atomicAdd(ap + 16 + q, PATH_NORM_C * o0[ms][1][r]);
            if ((q & 8) == 0) {
                const int v = q & 7;
                atomicAdd(ap + 32 + 3*v + 0, PATH_NORM_C * (o1v[ms][r][0] + s1x[r]*ttv[ms][r]));
                atomicAdd(ap + 32 + 3*v + 1, PATH_NORM_C * (o1v[ms][r][1] + s1y[r]*ttv[ms][r]));
                atomicAdd(ap + 32 + 3*v + 2, PATH_NORM_C * (o1v[ms][r][2] + s1z[r]*ttv[ms][r]));
            }
        }
    }

    if (lane < 32) atomicAdd(cnt + src_lds[wave*32 + lane], 1.0f);
}

__global__ __launch_bounds__(256) void finalize_kernel(
    const float* __restrict__ acc, const float* __restrict__ cnt,
    const float* __restrict__ node_attr, float* __restrict__ out)
{
    const int i = blockIdx.x * 256 + threadIdx.x;
    if (i >= NN * IND) return;
    const int n = i / IND;
    const float c = fmaxf(cnt[n], 1.0f);
    out[i] = acc[i] / c + node_attr[i];
}

extern "C" void kernel_launch(void* const* d_in, const int* in_sizes, int n_in,
                              void* d_out, int out_size, void* d_ws, size_t ws_size,
                              hipStream_t stream) {
    const float* node_attr = (const float*)d_in[0];
    const float* edge_attr = (const float*)d_in[1];
    const float* edge_sh   = (const float*)d_in[2];
    const float* fc_w1     = (const float*)d_in[3];
    const float* fc_b1     = (const float*)d_in[4];
    const float* fc_w2     = (const float*)d_in[5];
    const float* fc_b2     = (const float*)d_in[6];
    const int*   edge_index = (const int*)d_in[7];

    float* acc = (float*)d_ws;
    float* cnt = acc + (size_t)NN * IND;
    ushort* W1T = (ushort*)((char*)d_ws + 2280000);
    ushort* W2F = W1T + 64 * 64;

    hipMemsetAsync(d_ws, 0, ((size_t)NN * IND + NN) * sizeof(float), stream);

    prep_kernel<<<(64*64 + 100*1024 + 255) / 256, 256, 0, stream>>>(fc_w1, fc_w2, W1T, W2F);

    edge_kernel<<<NBLK, 256, 0, stream>>>(
        node_attr, edge_attr, edge_sh, fc_b1, fc_b2, edge_index, W1T, W2F, acc, cnt);

    finalize_kernel<<<(NN * IND + 255) / 256, 256, 0, stream>>>(
        acc, cnt, node_attr, (float*)d_out);
}

// Round 6
// 149.308 us; speedup vs baseline: 11.0850x; 1.2258x over previous
//
#include <hip/hip_runtime.h>

#define NN 10000
#define NE 160000
#define IND 56          // 32 + 3*8
#define WN 1600
#define EPB 128         // edges per block (4 waves x 32)
#define NBLK (NE / EPB) // 1250

typedef __attribute__((ext_vector_type(8))) short bf16x8;
typedef __attribute__((ext_vector_type(4))) float f32x4;

static constexpr float PATH_NORM_C = 0.15811388300841897f; // 1/sqrt(40)
static constexpr float CG_C        = 0.57735026918962576f; // 1/sqrt(3)

__device__ __forceinline__ uint32_t f2bf(float f) {
    uint32_t x = __float_as_uint(f);
    return (x + 0x7fffu + ((x >> 16) & 1u)) >> 16;   // RNE
}
__device__ __forceinline__ uint32_t pack2(float a, float b) {
    return f2bf(a) | (f2bf(b) << 16);
}

// ---- pre-pass: W1T (GEMM1 A-source) + W2F (GEMM2 B in fragment order) ------
// W1T[k][j] = fc_w1[j][k]  (64x64 bf16)
// W2F[t*1024 + kh*512 + l*8 + i] = fc_w2[k*WN + j],
//   j = t*16 + (l&15), k = kh*32 + (l>>4)*8 + i   -> per-tile loads contiguous
__global__ __launch_bounds__(256) void prep_kernel(
    const float* __restrict__ fc_w1, const float* __restrict__ fc_w2,
    ushort* __restrict__ W1T, ushort* __restrict__ W2F)
{
    int i = blockIdx.x * 256 + threadIdx.x;
    if (i < 64 * 64) {
        int k = i >> 6, j = i & 63;
        W1T[k * 64 + j] = (ushort)f2bf(fc_w1[j * 64 + k]);
    }
    int i2 = i - 64 * 64;
    if (i2 >= 0 && i2 < 100 * 1024) {
        int t  = i2 >> 10, r = i2 & 1023;
        int kh = r >> 9,  rr = r & 511;
        int l  = rr >> 3, ii = rr & 7;
        int j  = t * 16 + (l & 15);
        int k  = kh * 32 + ((l >> 4) << 3) + ii;
        W2F[i2] = (ushort)f2bf(fc_w2[k * WN + j]);
    }
}

__global__ __launch_bounds__(256, 3) void edge_kernel(
    const float* __restrict__ node_attr,
    const float* __restrict__ edge_attr,
    const float* __restrict__ edge_sh,
    const float* __restrict__ fc_b1,
    const float* __restrict__ fc_b2,
    const int*   __restrict__ edge_index,
    const ushort* __restrict__ W1T,
    const ushort* __restrict__ W2F,
    float* __restrict__ acc,
    float* __restrict__ cnt)
{
    // cf rows: 0..31 x0[u]; 32..55 s0*x1[u][m]; 56..63 y1[u]; 64 s0; 65..67 s1
    __shared__ float  cf[68][EPB];
    __shared__ int    src_lds[EPB];
    __shared__ __attribute__((aligned(16))) ushort pool[8192]; // GEMM1->GEMM2 relay

    const int tid  = threadIdx.x;
    const int wave = tid >> 6;
    const int lane = tid & 63;
    const int g    = lane >> 4;
    const int q    = lane & 15;
    const int E0   = blockIdx.x * EPB;

    // ---------------- preamble: per-edge coefficient table -------------------
    if (tid < EPB) {
        const int e    = tid;
        const int srcn = edge_index[E0 + e];
        const int dstn = edge_index[NE + E0 + e];
        src_lds[e] = srcn;
        const float4 sh = reinterpret_cast<const float4*>(edge_sh)[E0 + e];
        const float4* xp = reinterpret_cast<const float4*>(node_attr + (size_t)dstn * IND);
        float xr[56];
        #pragma unroll
        for (int i = 0; i < 14; ++i) {
            float4 v = xp[i];
            xr[4*i] = v.x; xr[4*i+1] = v.y; xr[4*i+2] = v.z; xr[4*i+3] = v.w;
        }
        #pragma unroll
        for (int u = 0; u < 32; ++u) cf[u][e] = xr[u];
        #pragma unroll
        for (int u = 0; u < 8; ++u) {
            cf[32 + 3*u + 0][e] = sh.x * xr[32 + 3*u + 0];
            cf[32 + 3*u + 1][e] = sh.x * xr[32 + 3*u + 1];
            cf[32 + 3*u + 2][e] = sh.x * xr[32 + 3*u + 2];
            cf[56 + u][e] = CG_C * (xr[32+3*u]*sh.y + xr[32+3*u+1]*sh.z + xr[32+3*u+2]*sh.w);
        }
        cf[64][e] = sh.x;
        cf[65][e] = sh.y;  cf[66][e] = sh.z;  cf[67][e] = sh.w;
    }

    // ---------------- GEMM1 via transposed MFMA: h_pre[k][e] -----------------
    f32x4 d1[2][4];
    #pragma unroll
    for (int mt = 0; mt < 4; ++mt) {
        const float4 b1v = *reinterpret_cast<const float4*>(fc_b1 + mt*16 + 4*g);
        #pragma unroll
        for (int ms = 0; ms < 2; ++ms)
            d1[ms][mt] = (f32x4){b1v.x, b1v.y, b1v.z, b1v.w};
    }

    #pragma unroll
    for (int kh = 0; kh < 2; ++kh) {
        bf16x8 bfr[2];
        #pragma unroll
        for (int ms = 0; ms < 2; ++ms) {
            const int e = E0 + wave*32 + ms*16 + q;
            const float* ap = edge_attr + (size_t)e * 64 + kh*32 + g*8;
            float4 f0 = *reinterpret_cast<const float4*>(ap);
            float4 f1 = *reinterpret_cast<const float4*>(ap + 4);
            union { uint32_t u[4]; bf16x8 v; } cv;
            cv.u[0] = pack2(f0.x, f0.y); cv.u[1] = pack2(f0.z, f0.w);
            cv.u[2] = pack2(f1.x, f1.y); cv.u[3] = pack2(f1.z, f1.w);
            bfr[ms] = cv.v;
        }
        #pragma unroll
        for (int mt = 0; mt < 4; ++mt) {
            bf16x8 afr = *reinterpret_cast<const bf16x8*>(W1T + (mt*16 + q)*64 + kh*32 + g*8);
            #pragma unroll
            for (int ms = 0; ms < 2; ++ms)
                d1[ms][mt] = __builtin_amdgcn_mfma_f32_16x16x32_bf16(afr, bfr[ms], d1[ms][mt], 0, 0, 0);
        }
    }
    // relu + bf16 pack into own-wave hbuf region of pool
    #pragma unroll
    for (int mt = 0; mt < 4; ++mt) {
        const int kg = 2*mt + (g >> 1);
        #pragma unroll
        for (int ms = 0; ms < 2; ++ms) {
            float v0 = fmaxf(d1[ms][mt][0], 0.f);
            float v1 = fmaxf(d1[ms][mt][1], 0.f);
            float v2 = fmaxf(d1[ms][mt][2], 0.f);
            float v3 = fmaxf(d1[ms][mt][3], 0.f);
            uint32_t* wp = reinterpret_cast<uint32_t*>(
                &pool[wave*2048 + ms*1024 + (kg*16 + q)*8 + 4*(g & 1)]);
            wp[0] = pack2(v0, v1);
            wp[1] = pack2(v2, v3);
        }
    }

    // read own-wave A-fragments back (same-wave ds order via lgkmcnt -> safe)
    bf16x8 af[2][2];
    #pragma unroll
    for (int ms = 0; ms < 2; ++ms)
        #pragma unroll
        for (int kh = 0; kh < 2; ++kh)
            af[ms][kh] = *reinterpret_cast<const bf16x8*>(
                &pool[wave*2048 + ms*1024 + ((kh*4 + g)*16 + q)*8]);

    // 4-deep named-slot prefetch pipeline for the W2F tile stream
    bf16x8 A0, A1, B0, B1, C0, C1, D0, D1;
    float  Ab, Bb, Cb, Db;
    auto load_slot = [&](int t, bf16x8& b0, bf16x8& b1, float& bb) {
        const ushort* p = W2F + (size_t)t * 1024 + lane * 8;
        b0 = *reinterpret_cast<const bf16x8*>(p);
        b1 = *reinterpret_cast<const bf16x8*>(p + 512);
        bb = fc_b2[t * 16 + q];
    };
    load_slot(0, A0, A1, Ab);
    load_slot(1, B0, B1, Bb);
    load_slot(2, C0, C1, Cb);
    load_slot(3, D0, D1, Db);

    __syncthreads();   // cf visible to all waves (single barrier in kernel)

    const int ebase = wave*32 + 4*g;
    f32x4 s0v[2];
    s0v[0] = *reinterpret_cast<const f32x4*>(&cf[64][ebase]);
    s0v[1] = *reinterpret_cast<const f32x4*>(&cf[64][ebase + 16]);

    float o0[2][2][4];
    float ttv[2][4];
    float o1v[2][4][3];
    #pragma unroll
    for (int ms = 0; ms < 2; ++ms) {
        #pragma unroll
        for (int r = 0; r < 4; ++r) {
            o0[ms][0][r] = 0.f; o0[ms][1][r] = 0.f; ttv[ms][r] = 0.f;
            o1v[ms][r][0] = 0.f; o1v[ms][r][1] = 0.f; o1v[ms][r][2] = 0.f;
        }
    }

    auto mfma2 = [&](const bf16x8& b0, const bf16x8& b1, float b2v, f32x4* accv) {
        #pragma unroll
        for (int ms = 0; ms < 2; ++ms) {
            f32x4 a = (f32x4){b2v, b2v, b2v, b2v};
            a = __builtin_amdgcn_mfma_f32_16x16x32_bf16(af[ms][0], b0, a, 0, 0, 0);
            a = __builtin_amdgcn_mfma_f32_16x16x32_bf16(af[ms][1], b1, a, 0, 0, 0);
            accv[ms] = a;
        }
    };

    const int qh = q >> 3;

    // ---- region 1: tiles 0..63 (chunks of 4), coef s0*x0[u], out0 -----------
    #pragma unroll 1
    for (int c = 0; c < 16; ++c) {
        const int t4 = 4*c;
        const int u0 = 2*c, u1 = 2*c + 1;
        f32x4 c00 = *reinterpret_cast<const f32x4*>(&cf[u0][ebase]);
        f32x4 c01 = *reinterpret_cast<const f32x4*>(&cf[u0][ebase + 16]);
        f32x4 c10 = *reinterpret_cast<const f32x4*>(&cf[u1][ebase]);
        f32x4 c11 = *reinterpret_cast<const f32x4*>(&cf[u1][ebase + 16]);
        f32x4 w2[2];

        mfma2(A0, A1, Ab, w2);  load_slot(t4 + 4, A0, A1, Ab);
        #pragma unroll
        for (int r = 0; r < 4; ++r) {
            o0[0][0][r] = fmaf(s0v[0][r]*c00[r], w2[0][r], o0[0][0][r]);
            o0[1][0][r] = fmaf(s0v[1][r]*c01[r], w2[1][r], o0[1][0][r]);
        }
        mfma2(B0, B1, Bb, w2);  load_slot(t4 + 5, B0, B1, Bb);
        #pragma unroll
        for (int r = 0; r < 4; ++r) {
            o0[0][1][r] = fmaf(s0v[0][r]*c00[r], w2[0][r], o0[0][1][r]);
            o0[1][1][r] = fmaf(s0v[1][r]*c01[r], w2[1][r], o0[1][1][r]);
        }
        mfma2(C0, C1, Cb, w2);  load_slot(t4 + 6, C0, C1, Cb);
        #pragma unroll
        for (int r = 0; r < 4; ++r) {
            o0[0][0][r] = fmaf(s0v[0][r]*c10[r], w2[0][r], o0[0][0][r]);
            o0[1][0][r] = fmaf(s0v[1][r]*c11[r], w2[1][r], o0[1][0][r]);
        }
        mfma2(D0, D1, Db, w2);  load_slot(t4 + 7, D0, D1, Db);
        #pragma unroll
        for (int r = 0; r < 4; ++r) {
            o0[0][1][r] = fmaf(s0v[0][r]*c10[r], w2[0][r], o0[0][1][r]);
            o0[1][1][r] = fmaf(s0v[1][r]*c11[r], w2[1][r], o0[1][1][r]);
        }
    }

    // ---- region 2: tiles 64..79, u = 8d+2*tc+qh, coef x0[u], tt -------------
    #pragma unroll 1
    for (int d = 0; d < 4; ++d) {
        const int t4 = 64 + 4*d;
        f32x4 w2[2];

        mfma2(A0, A1, Ab, w2);  load_slot(t4 + 4, A0, A1, Ab);
        {
            const int u = 8*d + qh;
            #pragma unroll
            for (int ms = 0; ms < 2; ++ms) {
                f32x4 cfv = *reinterpret_cast<const f32x4*>(&cf[u][ebase + ms*16]);
                #pragma unroll
                for (int r = 0; r < 4; ++r) ttv[ms][r] = fmaf(cfv[r], w2[ms][r], ttv[ms][r]);
            }
        }
        mfma2(B0, B1, Bb, w2);  load_slot(t4 + 5, B0, B1, Bb);
        {
            const int u = 8*d + 2 + qh;
            #pragma unroll
            for (int ms = 0; ms < 2; ++ms) {
                f32x4 cfv = *reinterpret_cast<const f32x4*>(&cf[u][ebase + ms*16]);
                #pragma unroll
                for (int r = 0; r < 4; ++r) ttv[ms][r] = fmaf(cfv[r], w2[ms][r], ttv[ms][r]);
            }
        }
        mfma2(C0, C1, Cb, w2);  load_slot(t4 + 6, C0, C1, Cb);
        {
            const int u = 8*d + 4 + qh;
            #pragma unroll
            for (int ms = 0; ms < 2; ++ms) {
                f32x4 cfv = *reinterpret_cast<const f32x4*>(&cf[u][ebase + ms*16]);
                #pragma unroll
                for (int r = 0; r < 4; ++r) ttv[ms][r] = fmaf(cfv[r], w2[ms][r], ttv[ms][r]);
            }
        }
        mfma2(D0, D1, Db, w2);  load_slot(t4 + 7, D0, D1, Db);
        {
            const int u = 8*d + 6 + qh;
            #pragma unroll
            for (int ms = 0; ms < 2; ++ms) {
                f32x4 cfv = *reinterpret_cast<const f32x4*>(&cf[u][ebase + ms*16]);
                #pragma unroll
                for (int r = 0; r < 4; ++r) ttv[ms][r] = fmaf(cfv[r], w2[ms][r], ttv[ms][r]);
            }
        }
    }

    // ---- region 3: tiles 80..83, u = 2*tc+qh, coef s0*x1[u][m], o1 ----------
    {
        f32x4 w2[2];
        #define R3_BODY(TC)                                                         \
            {                                                                       \
                const int u = 2*(TC) + qh;                                          \
                _Pragma("unroll")                                                   \
                for (int ms = 0; ms < 2; ++ms)                                      \
                    _Pragma("unroll")                                               \
                    for (int m = 0; m < 3; ++m) {                                   \
                        f32x4 cfv = *reinterpret_cast<const f32x4*>(                \
                            &cf[32 + u*3 + m][ebase + ms*16]);                      \
                        _Pragma("unroll")                                           \
                        for (int r = 0; r < 4; ++r)                                 \
                            o1v[ms][r][m] = fmaf(cfv[r], w2[ms][r], o1v[ms][r][m]); \
                    }                                                               \
            }
        mfma2(A0, A1, Ab, w2);  load_slot(84, A0, A1, Ab);  R3_BODY(0)
        mfma2(B0, B1, Bb, w2);  load_slot(85, B0, B1, Bb);  R3_BODY(1)
        mfma2(C0, C1, Cb, w2);  load_slot(86, C0, C1, Cb);  R3_BODY(2)
        mfma2(D0, D1, Db, w2);  load_slot(87, D0, D1, Db);  R3_BODY(3)
        #undef R3_BODY
    }

    // ---- region 4: tiles 84..99, u4 = 2d+(tc>>1), coef y1[u4], out0 ---------
    #pragma unroll 1
    for (int d = 0; d < 4; ++d) {
        const int t4 = 84 + 4*d;
        const int u0 = 2*d, u1 = 2*d + 1;
        f32x4 c00 = *reinterpret_cast<const f32x4*>(&cf[56 + u0][ebase]);
        f32x4 c01 = *reinterpret_cast<const f32x4*>(&cf[56 + u0][ebase + 16]);
        f32x4 c10 = *reinterpret_cast<const f32x4*>(&cf[56 + u1][ebase]);
        f32x4 c11 = *reinterpret_cast<const f32x4*>(&cf[56 + u1][ebase + 16]);
        f32x4 w2[2];
        int tn;

        mfma2(A0, A1, Ab, w2);  tn = t4 + 4; load_slot(tn < 100 ? tn : 99, A0, A1, Ab);
        #pragma unroll
        for (int r = 0; r < 4; ++r) {
            o0[0][0][r] = fmaf(c00[r], w2[0][r], o0[0][0][r]);
            o0[1][0][r] = fmaf(c01[r], w2[1][r], o0[1][0][r]);
        }
        mfma2(B0, B1, Bb, w2);  tn = t4 + 5; load_slot(tn < 100 ? tn : 99, B0, B1, Bb);
        #pragma unroll
        for (int r = 0; r < 4; ++r) {
            o0[0][1][r] = fmaf(c00[r], w2[0][r], o0[0][1][r]);
            o0[1][1][r] = fmaf(c01[r], w2[1][r], o0[1][1][r]);
        }
        mfma2(C0, C1, Cb, w2);  tn = t4 + 6; load_slot(tn < 100 ? tn : 99, C0, C1, Cb);
        #pragma unroll
        for (int r = 0; r < 4; ++r) {
            o0[0][0][r] = fmaf(c10[r], w2[0][r], o0[0][0][r]);
            o0[1][0][r] = fmaf(c11[r], w2[1][r], o0[1][0][r]);
        }
        mfma2(D0, D1, Db, w2);  tn = t4 + 7; load_slot(tn < 100 ? tn : 99, D0, D1, Db);
        #pragma unroll
        for (int r = 0; r < 4; ++r) {
            o0[0][1][r] = fmaf(c10[r], w2[0][r], o0[0][1][r]);
            o0[1][1][r] = fmaf(c11[r], w2[1][r], o0[1][1][r]);
        }
    }

    // ---- finish: reduce u-halves (lane ^ 8), atomics ------------------------
    #pragma unroll
    for (int ms = 0; ms < 2; ++ms)
        #pragma unroll
        for (int r = 0; r < 4; ++r) {
            ttv[ms][r] += __shfl_xor(ttv[ms][r], 8, 64);
            #pragma unroll
            for (int m = 0; m < 3; ++m)
                o1v[ms][r][m] += __shfl_xor(o1v[ms][r][m], 8, 64);
        }

    #pragma unroll
    for (int ms = 0; ms < 2; ++ms) {
        const int eb = ebase + ms*16;
        const int4 srcv = *reinterpret_cast<const int4*>(&src_lds[eb]);
        const f32x4 s1x = *reinterpret_cast<const f32x4*>(&cf[65][eb]);
        const f32x4 s1y = *reinterpret_cast<const f32x4*>(&cf[66][eb]);
        const f32x4 s1z = *reinterpret_cast<const f32x4*>(&cf[67][eb]);
        #pragma unroll
        for (int r = 0; r < 4; ++r) {
            const int node = (r == 0) ? srcv.x : (r == 1) ? srcv.y : (r == 2) ? srcv.z : srcv.w;
            float* ap = acc + (size_t)node * IND;
            atomicAdd(ap + q,      PATH_NORM_C * o0[ms][0][r]);
            atomicAdd(ap + 16 + q, PATH_NORM_C * o0[ms][1][r]);
            if ((q & 8) == 0) {
                const int v = q & 7;
                atomicAdd(ap + 32 + 3*v + 0, PATH_NORM_C * (o1v[ms][r][0] + s1x[r]*ttv[ms][r]));
                atomicAdd(ap + 32 + 3*v + 1, PATH_NORM_C * (o1v[ms][r][1] + s1y[r]*ttv[ms][r]));
                atomicAdd(ap + 32 + 3*v + 2, PATH_NORM_C * (o1v[ms][r][2] + s1z[r]*ttv[ms][r]));
            }
        }
    }

    if (lane < 32) atomicAdd(cnt + src_lds[wave*32 + lane], 1.0f);
}

__global__ __launch_bounds__(256) void finalize_kernel(
    const float* __restrict__ acc, const float* __restrict__ cnt,
    const float* __restrict__ node_attr, float* __restrict__ out)
{
    const int i = blockIdx.x * 256 + threadIdx.x;
    if (i >= NN * IND) return;
    const int n = i / IND;
    const float c = fmaxf(cnt[n], 1.0f);
    out[i] = acc[i] / c + node_attr[i];
}

extern "C" void kernel_launch(void* const* d_in, const int* in_sizes, int n_in,
                              void* d_out, int out_size, void* d_ws, size_t ws_size,
                              hipStream_t stream) {
    const float* node_attr = (const float*)d_in[0];
    const float* edge_attr = (const float*)d_in[1];
    const float* edge_sh   = (const float*)d_in[2];
    const float* fc_w1     = (const float*)d_in[3];
    const float* fc_b1     = (const float*)d_in[4];
    const float* fc_w2     = (const float*)d_in[5];
    const float* fc_b2     = (const float*)d_in[6];
    const int*   edge_index = (const int*)d_in[7];

    float* acc = (float*)d_ws;
    float* cnt = acc + (size_t)NN * IND;
    ushort* W1T = (ushort*)((char*)d_ws + 2280000);
    ushort* W2F = W1T + 64 * 64;

    hipMemsetAsync(d_ws, 0, ((size_t)NN * IND + NN) * sizeof(float), stream);

    prep_kernel<<<(64*64 + 100*1024 + 255) / 256, 256, 0, stream>>>(fc_w1, fc_w2, W1T, W2F);

    edge_kernel<<<NBLK, 256, 0, stream>>>(
        node_attr, edge_attr, edge_sh, fc_b1, fc_b2, edge_index, W1T, W2F, acc, cnt);

    finalize_kernel<<<(NN * IND + 255) / 256, 256, 0, stream>>>(
        acc, cnt, node_attr, (float*)d_out);
}